// Round 7
// baseline (1028.910 us; speedup 1.0000x reference)
//
#include <hip/hip_runtime.h>
#include <hip/hip_bf16.h>

// Sumformer inner block: 9-GEMM bf16 MFMA pipeline + segment-mean + gather.
// R7: 2-phase double-buffered K-pipeline (T3-minimal). Stage next K-tile
// BEFORE computing current one; drain vmcnt(0) + raw s_barrier AFTER the
// MFMAs so global->LDS latency hides under compute (the R6 structure drained
// before compute -- the m97 ~20% stall, worse here with only 8 K-iters).
// LDS 2x32KB. Barrier discipline: asm vmcnt(0)+"memory" before s_barrier,
// empty memory-clobber asm after (prevents ds_read hoist across barrier).

typedef __attribute__((ext_vector_type(8))) short bf16x8;
typedef __attribute__((ext_vector_type(4))) float f32x4;

#define N_NODES 131072
#define NUM_G   1024

__device__ __forceinline__ float lrelu_f(float v) { return v >= 0.f ? v : 0.01f * v; }
__device__ __forceinline__ float bf2f(__hip_bfloat16 h) { return __bfloat162float(h); }

__global__ void sentinel(float* out, float v) {
  if (blockIdx.x == 0 && threadIdx.x == 0) out[0] = v;
}

// WT[p][k] = bf16(W[k][p]);  W is [K][P]
__global__ void wt_conv(const float* __restrict__ W, __hip_bfloat16* __restrict__ WT, int K, int P) {
  int idx = blockIdx.x * 256 + threadIdx.x;
  if (idx >= K * P) return;
  int p = idx / K;
  int k = idx - p * K;
  WT[idx] = __float2bfloat16(W[(size_t)k * P + p]);
}

__global__ void xconv(const float* __restrict__ x, __hip_bfloat16* __restrict__ xb, int n4) {
  int i = blockIdx.x * 256 + threadIdx.x;
  if (i >= n4) return;
  float4 v = reinterpret_cast<const float4*>(x)[i];
  union { __hip_bfloat16 h[4]; uint2 u; } o;
  o.h[0] = __float2bfloat16(v.x); o.h[1] = __float2bfloat16(v.y);
  o.h[2] = __float2bfloat16(v.z); o.h[3] = __float2bfloat16(v.w);
  reinterpret_cast<uint2*>(xb)[i] = o.u;
}

template<int FIRST>
__global__ void seg_accum(const __hip_bfloat16* __restrict__ nechunk,
                          const int* __restrict__ ids,
                          float* __restrict__ sums, int rb, int ch) {
  int g = blockIdx.x;
  int k = threadIdx.x;
  int lo = 0, hi = N_NODES;
  while (lo < hi) { int m = (lo + hi) >> 1; if (ids[m] < g) lo = m + 1; else hi = m; }
  int s = lo;
  hi = N_NODES;
  while (lo < hi) { int m = (lo + hi) >> 1; if (ids[m] < g + 1) lo = m + 1; else hi = m; }
  int e = lo;
  int s2 = s > rb ? s : rb;
  int e2 = e < rb + ch ? e : rb + ch;
  float acc = 0.f;
  for (int r = s2; r < e2; ++r)
    acc += bf2f(nechunk[(size_t)(r - rb) * 256 + k]);
  if (FIRST) sums[g * 256 + k] = acc;
  else if (e2 > s2) sums[g * 256 + k] += acc;
}

__global__ void sigma_fin(const float* __restrict__ sums,
                          const int* __restrict__ ids,
                          __hip_bfloat16* __restrict__ sigma) {
  int g = blockIdx.x;
  int k = threadIdx.x;
  int lo = 0, hi = N_NODES;
  while (lo < hi) { int m = (lo + hi) >> 1; if (ids[m] < g) lo = m + 1; else hi = m; }
  int s = lo;
  hi = N_NODES;
  while (lo < hi) { int m = (lo + hi) >> 1; if (ids[m] < g + 1) lo = m + 1; else hi = m; }
  int e = lo;
  float c = (float)(e - s);
  sigma[g * 256 + k] = __float2bfloat16(sums[g * 256 + k] / fmaxf(c, 1.f));
}

// Fused GEMM: out[M,P] = act(A[M,K] @ BT[P,K]^T + bias (+ extra[bids[row]]))
// 128x128 tile, 4 waves (2x2 of 64x64), BK=64, mfma_f32_16x16x32_bf16.
// Double-buffered: STAGE(next) -> ds_read+MFMA(cur) -> vmcnt(0)+barrier.
// XOR swizzle via pre-swizzled global source (LDS dest stays linear).
template<int ACT, int BF16OUT, int ADD_EXTRA>
__global__ __launch_bounds__(256)
void gemm_mfma(const __hip_bfloat16* __restrict__ A,
               const __hip_bfloat16* __restrict__ BT,
               const float* __restrict__ bias,
               const float* __restrict__ extra,
               const int* __restrict__ bids,
               void* __restrict__ out,
               int K, int P) {
  __shared__ __attribute__((aligned(128))) char smem[65536];

  const int tid  = threadIdx.x;
  const int lane = tid & 63;
  const int wave = tid >> 6;
  const int brow = blockIdx.x << 7;
  const int bcol = blockIdx.y << 7;
  const int wm = (wave >> 1) << 6;
  const int wn = (wave & 1) << 6;

  const int rsub = lane >> 3;           // row within 8-row segment
  const int csrc = (lane & 7) ^ rsub;   // pre-swizzled source 16B-chunk

  f32x4 acc[4][4] = {};
  const int nt = K >> 6;

  auto STAGE = [&](int buf, int k0) {
    char* sA = smem + (buf << 15);
    char* sB = sA + 16384;
#pragma unroll
    for (int i = 0; i < 4; ++i) {
      int seg = (wave << 2) + i;        // 0..15 -> tile rows seg*8..seg*8+7
      int row = (seg << 3) + rsub;
      const __hip_bfloat16* gpA = A + (size_t)(brow + row) * K + (k0 + (csrc << 3));
      __builtin_amdgcn_global_load_lds(
          (const __attribute__((address_space(1))) void*)gpA,
          (__attribute__((address_space(3))) void*)(sA + (seg << 10)),
          16, 0, 0);
      const __hip_bfloat16* gpB = BT + (size_t)(bcol + row) * K + (k0 + (csrc << 3));
      __builtin_amdgcn_global_load_lds(
          (const __attribute__((address_space(1))) void*)gpB,
          (__attribute__((address_space(3))) void*)(sB + (seg << 10)),
          16, 0, 0);
    }
  };

  // prologue: stage tile 0, drain, barrier
  STAGE(0, 0);
  asm volatile("s_waitcnt vmcnt(0)" ::: "memory");
  __builtin_amdgcn_s_barrier();
  asm volatile("" ::: "memory");

  int cur = 0;
  for (int t = 0; t < nt; ++t) {
    if (t + 1 < nt) STAGE(cur ^ 1, (t + 1) << 6);   // in flight during compute

    char* sA = smem + (cur << 15);
    char* sB = sA + 16384;
    const int r15 = lane & 15;
#pragma unroll
    for (int ks = 0; ks < 2; ++ks) {
      const int c = (ks << 2) + (lane >> 4);  // logical k-chunk 0..7
      bf16x8 af[4], bfv[4];
#pragma unroll
      for (int f = 0; f < 4; ++f) {
        int ar = wm + (f << 4) + r15;
        af[f]  = *reinterpret_cast<const bf16x8*>(sA + ar * 128 + ((c ^ (ar & 7)) << 4));
        int br = wn + (f << 4) + r15;
        bfv[f] = *reinterpret_cast<const bf16x8*>(sB + br * 128 + ((c ^ (br & 7)) << 4));
      }
#pragma unroll
      for (int fm = 0; fm < 4; ++fm)
#pragma unroll
        for (int fn = 0; fn < 4; ++fn)
          acc[fm][fn] = __builtin_amdgcn_mfma_f32_16x16x32_bf16(af[fm], bfv[fn], acc[fm][fn], 0, 0, 0);
    }

    if (t + 1 < nt) {
      asm volatile("s_waitcnt vmcnt(0)" ::: "memory");  // next tile fully staged
      __builtin_amdgcn_s_barrier();                     // all waves: reads done, stage done
      asm volatile("" ::: "memory");                    // no ds_read hoist above barrier
      cur ^= 1;
    }
  }

  // epilogue: C/D layout col=lane&15, row=(lane>>4)*4+reg   [m89-verified]
  const int r15 = lane & 15;
  const int hi4 = (lane >> 4) << 2;
#pragma unroll
  for (int fn = 0; fn < 4; ++fn) {
    int col = bcol + wn + (fn << 4) + r15;
    float bv = bias[col];
#pragma unroll
    for (int fm = 0; fm < 4; ++fm) {
      int row0 = brow + wm + (fm << 4) + hi4;
#pragma unroll
      for (int r = 0; r < 4; ++r) {
        float v = acc[fm][fn][r] + bv;
        if (ADD_EXTRA) {
          int b = bids[row0 + r];
          v += extra[(size_t)b * P + col];
        }
        if (ACT) v = lrelu_f(v);
        size_t oidx = (size_t)(row0 + r) * P + col;
        if (BF16OUT) reinterpret_cast<__hip_bfloat16*>(out)[oidx] = __float2bfloat16(v);
        else         reinterpret_cast<float*>(out)[oidx] = v;
      }
    }
  }
}

extern "C" void kernel_launch(void* const* d_in, const int* in_sizes, int n_in,
                              void* d_out, int out_size, void* d_ws, size_t ws_size,
                              hipStream_t stream) {
  const float* x      = (const float*)d_in[0];
  const int*   bids   = (const int*)  d_in[1];
  const float* ge_W0  = (const float*)d_in[2];
  const float* ge_b0  = (const float*)d_in[3];
  const float* ge_Wh  = (const float*)d_in[4];
  const float* ge_bh  = (const float*)d_in[5];
  const float* ge_Wo  = (const float*)d_in[6];
  const float* ge_bo  = (const float*)d_in[7];
  const float* in_W   = (const float*)d_in[8];
  const float* in_b   = (const float*)d_in[9];
  const float* ag_W   = (const float*)d_in[10];
  const float* ag_b   = (const float*)d_in[11];
  const float* psi_Wh = (const float*)d_in[12];
  const float* psi_bh = (const float*)d_in[13];
  const float* psi_Wo = (const float*)d_in[14];
  const float* psi_bo = (const float*)d_in[15];

  char* ws = (char*)d_ws;
  __hip_bfloat16* geW0T   = (__hip_bfloat16*)(ws + 0);        // [512][128]
  __hip_bfloat16* geWh0T  = (__hip_bfloat16*)(ws + 131072);   // [512][512]
  __hip_bfloat16* geWh1T  = (__hip_bfloat16*)(ws + 655360);   // [512][512]
  __hip_bfloat16* geWoT   = (__hip_bfloat16*)(ws + 1179648);  // [256][512]
  __hip_bfloat16* inWT    = (__hip_bfloat16*)(ws + 1441792);  // [512][128]
  __hip_bfloat16* agWT    = (__hip_bfloat16*)(ws + 1572864);  // [512][256]
  __hip_bfloat16* psiWh0T = (__hip_bfloat16*)(ws + 1835008);  // [512][512]
  __hip_bfloat16* psiWh1T = (__hip_bfloat16*)(ws + 2359296);  // [512][512]
  __hip_bfloat16* psiWh2T = (__hip_bfloat16*)(ws + 2883584);  // [512][512]
  __hip_bfloat16* psiWoT  = (__hip_bfloat16*)(ws + 3407872);  // [128][512]
  __hip_bfloat16* sigma   = (__hip_bfloat16*)(ws + 3538944);  // [1024][256] bf16
  float*          sh      = (float*)         (ws + 4063232);  // [1024][512] f32
  float*          sums    = (float*)         (ws + 6160384);  // [1024][256] f32
  const size_t base = 7340032;  // 7 MiB

  size_t CH = 0;
  {
    const size_t cands[11] = {131072, 65536, 32768, 16384, 8192, 4096, 2048, 1024, 512, 256, 128};
    for (int i = 0; i < 11; ++i)
      if (ws_size >= base + cands[i] * 2304ull) { CH = cands[i]; break; }
  }
  if (CH == 0) {
    sentinel<<<1, 64, 0, stream>>>((float*)d_out, 100000000.f + (float)(ws_size / 1024));
    return;
  }

  __hip_bfloat16* xc  = (__hip_bfloat16*)(ws + base);
  __hip_bfloat16* pp0 = (__hip_bfloat16*)(ws + base + CH * 256);
  __hip_bfloat16* pp1 = (__hip_bfloat16*)(ws + base + CH * 256 + CH * 1024);

  dim3 blk(256);
  const int nch = (int)(N_NODES / CH);
  dim3 g4((unsigned)(CH >> 7), 4), g2((unsigned)(CH >> 7), 2), g1((unsigned)(CH >> 7), 1);

  // ---- weight conversions (all ten) ----
  wt_conv<<<256,  blk, 0, stream>>>(ge_W0,            geW0T,   128, 512);
  wt_conv<<<1024, blk, 0, stream>>>(ge_Wh,            geWh0T,  512, 512);
  wt_conv<<<1024, blk, 0, stream>>>(ge_Wh + 262144,   geWh1T,  512, 512);
  wt_conv<<<512,  blk, 0, stream>>>(ge_Wo,            geWoT,   512, 256);
  wt_conv<<<256,  blk, 0, stream>>>(in_W,             inWT,    128, 512);
  wt_conv<<<512,  blk, 0, stream>>>(ag_W,             agWT,    256, 512);
  wt_conv<<<1024, blk, 0, stream>>>(psi_Wh,           psiWh0T, 512, 512);
  wt_conv<<<1024, blk, 0, stream>>>(psi_Wh + 262144,  psiWh1T, 512, 512);
  wt_conv<<<1024, blk, 0, stream>>>(psi_Wh + 524288,  psiWh2T, 512, 512);
  wt_conv<<<256,  blk, 0, stream>>>(psi_Wo,           psiWoT,  512, 128);

  for (int c = 0; c < nch; ++c) {
    const size_t rb = (size_t)c * CH;
    xconv<<<(unsigned)(CH >> 3), blk, 0, stream>>>(x + rb * 128, xc, (int)(CH * 32));
    gemm_mfma<1,1,0><<<g4, blk, 0, stream>>>(xc,  geW0T,  ge_b0,     nullptr, nullptr, pp0, 128, 512);
    gemm_mfma<1,1,0><<<g4, blk, 0, stream>>>(pp0, geWh0T, ge_bh,     nullptr, nullptr, pp1, 512, 512);
    gemm_mfma<1,1,0><<<g4, blk, 0, stream>>>(pp1, geWh1T, ge_bh+512, nullptr, nullptr, pp0, 512, 512);
    gemm_mfma<1,1,0><<<g2, blk, 0, stream>>>(pp0, geWoT,  ge_bo,     nullptr, nullptr, pp1, 512, 256);
    if (c == 0) seg_accum<1><<<NUM_G, blk, 0, stream>>>(pp1, bids, sums, (int)rb, (int)CH);
    else        seg_accum<0><<<NUM_G, blk, 0, stream>>>(pp1, bids, sums, (int)rb, (int)CH);
  }

  sigma_fin<<<NUM_G, blk, 0, stream>>>(sums, bids, sigma);
  gemm_mfma<0,0,0><<<dim3(8,4), blk, 0, stream>>>(sigma, agWT, ag_b, nullptr, nullptr, sh, 256, 512);

  for (int c = 0; c < nch; ++c) {
    const size_t rb = (size_t)c * CH;
    xconv<<<(unsigned)(CH >> 3), blk, 0, stream>>>(x + rb * 128, xc, (int)(CH * 32));
    gemm_mfma<1,1,1><<<g4, blk, 0, stream>>>(xc,  inWT,    in_b,        sh,      bids + rb, pp0, 128, 512);
    gemm_mfma<1,1,0><<<g4, blk, 0, stream>>>(pp0, psiWh0T, psi_bh,      nullptr, nullptr,   pp1, 512, 512);
    gemm_mfma<1,1,0><<<g4, blk, 0, stream>>>(pp1, psiWh1T, psi_bh+512,  nullptr, nullptr,   pp0, 512, 512);
    gemm_mfma<1,1,0><<<g4, blk, 0, stream>>>(pp0, psiWh2T, psi_bh+1024, nullptr, nullptr,   pp1, 512, 512);
    gemm_mfma<0,0,0><<<g1, blk, 0, stream>>>(pp1, psiWoT,  psi_bo,      nullptr, nullptr,
                                             (float*)d_out + rb * 128, 512, 128);
  }
}

// Round 8
// 994.159 us; speedup vs baseline: 1.0350x; 1.0350x over previous
//
#include <hip/hip_runtime.h>
#include <hip/hip_bf16.h>

// Sumformer inner block: 9-GEMM bf16 MFMA pipeline + segment-mean + gather.
// R8: (1) counted-vmcnt deep pipeline (T4): 5 LDS buffers, BK=32, stage tile
// t+3 each iter, s_waitcnt vmcnt(12) -> 12 loads in flight ACROSS the barrier
// (R6/R7 drained vmcnt(0) every iter = the ~20% stall). One barrier/iter.
// Buffer safety: writer hits buf (t+3)%5; concurrent readers touch t-1/t only
// (distinct mod 5). Tail vmcnt steps 12/8/4/0.
// (2) grid transposed: bcol fast axis -> consecutive blocks share the A panel
// (R7 FETCH 133MB/dispatch = A streamed 4x; predict ~70MB).
// (3) wt_conv -> LDS-tiled transpose (both sides coalesced).
// Swizzle (BK=32, 4 chunks/row): physical chunk p of row r holds global chunk
// p ^ ((r>>1)&3); read of logical c fetches c ^ ((r>>1)&3). 16 consecutive
// rows -> 8 distinct bank-groups (2-way, free).

typedef __attribute__((ext_vector_type(8))) short bf16x8;
typedef __attribute__((ext_vector_type(4))) float f32x4;

#define N_NODES 131072
#define NUM_G   1024

__device__ __forceinline__ float lrelu_f(float v) { return v >= 0.f ? v : 0.01f * v; }
__device__ __forceinline__ float bf2f(__hip_bfloat16 h) { return __bfloat162float(h); }

__global__ void sentinel(float* out, float v) {
  if (blockIdx.x == 0 && threadIdx.x == 0) out[0] = v;
}

// WT[p][k] = bf16(W[k][p]);  W is [K][P].  LDS-tiled 32x32 transpose.
__global__ void wt_conv(const float* __restrict__ W, __hip_bfloat16* __restrict__ WT, int K, int P) {
  __shared__ float tile[32][33];
  const int p0 = blockIdx.x << 5, k0 = blockIdx.y << 5;
  const int tx = threadIdx.x & 31, ty = threadIdx.x >> 5;   // 256 thr
#pragma unroll
  for (int i = 0; i < 4; ++i) {
    int r = ty + (i << 3);
    tile[r][tx] = W[(size_t)(k0 + r) * P + p0 + tx];
  }
  __syncthreads();
#pragma unroll
  for (int i = 0; i < 4; ++i) {
    int r = ty + (i << 3);
    WT[(size_t)(p0 + r) * K + k0 + tx] = __float2bfloat16(tile[tx][r]);
  }
}

__global__ void xconv(const float* __restrict__ x, __hip_bfloat16* __restrict__ xb, int n4) {
  int i = blockIdx.x * 256 + threadIdx.x;
  if (i >= n4) return;
  float4 v = reinterpret_cast<const float4*>(x)[i];
  union { __hip_bfloat16 h[4]; uint2 u; } o;
  o.h[0] = __float2bfloat16(v.x); o.h[1] = __float2bfloat16(v.y);
  o.h[2] = __float2bfloat16(v.z); o.h[3] = __float2bfloat16(v.w);
  reinterpret_cast<uint2*>(xb)[i] = o.u;
}

template<int FIRST>
__global__ void seg_accum(const __hip_bfloat16* __restrict__ nechunk,
                          const int* __restrict__ ids,
                          float* __restrict__ sums, int rb, int ch) {
  int g = blockIdx.x;
  int k = threadIdx.x;
  int lo = 0, hi = N_NODES;
  while (lo < hi) { int m = (lo + hi) >> 1; if (ids[m] < g) lo = m + 1; else hi = m; }
  int s = lo;
  hi = N_NODES;
  while (lo < hi) { int m = (lo + hi) >> 1; if (ids[m] < g + 1) lo = m + 1; else hi = m; }
  int e = lo;
  int s2 = s > rb ? s : rb;
  int e2 = e < rb + ch ? e : rb + ch;
  float acc = 0.f;
  for (int r = s2; r < e2; ++r)
    acc += bf2f(nechunk[(size_t)(r - rb) * 256 + k]);
  if (FIRST) sums[g * 256 + k] = acc;
  else if (e2 > s2) sums[g * 256 + k] += acc;
}

__global__ void sigma_fin(const float* __restrict__ sums,
                          const int* __restrict__ ids,
                          __hip_bfloat16* __restrict__ sigma) {
  int g = blockIdx.x;
  int k = threadIdx.x;
  int lo = 0, hi = N_NODES;
  while (lo < hi) { int m = (lo + hi) >> 1; if (ids[m] < g) lo = m + 1; else hi = m; }
  int s = lo;
  hi = N_NODES;
  while (lo < hi) { int m = (lo + hi) >> 1; if (ids[m] < g + 1) lo = m + 1; else hi = m; }
  int e = lo;
  float c = (float)(e - s);
  sigma[g * 256 + k] = __float2bfloat16(sums[g * 256 + k] / fmaxf(c, 1.f));
}

// Fused GEMM: out[M,P] = act(A[M,K] @ BT[P,K]^T + bias (+ extra[bids[row]]))
// 128x128 tile, 4 waves (2x2 of 64x64), BK=32, 5-buffer depth-3 pipeline.
// grid: blockIdx.x = column block (fast), blockIdx.y = row block.
template<int ACT, int BF16OUT, int ADD_EXTRA>
__global__ __launch_bounds__(256)
void gemm_mfma(const __hip_bfloat16* __restrict__ A,
               const __hip_bfloat16* __restrict__ BT,
               const float* __restrict__ bias,
               const float* __restrict__ extra,
               const int* __restrict__ bids,
               void* __restrict__ out,
               int K, int P) {
  __shared__ __attribute__((aligned(128))) char smem[81920];   // 5 x (A 8KB + B 8KB)

  const int tid  = threadIdx.x;
  const int lane = tid & 63;
  const int wave = tid >> 6;
  const int bcol = blockIdx.x << 7;   // fast axis: blocks sharing A-rows adjacent
  const int brow = blockIdx.y << 7;
  const int wm = (wave >> 1) << 6;
  const int wn = (wave & 1) << 6;

  const int lrow = lane >> 2;                       // row within 16-row segment
  const int gc   = (lane & 3) ^ ((lane >> 3) & 3);  // pre-swizzled source chunk

  f32x4 acc[4][4] = {};
  const int nt = K >> 5;   // BK=32; all K here are >=128 -> nt>=4

  auto STAGE = [&](int t) {
    char* sA = smem + (t % 5) * 16384;
    char* sB = sA + 8192;
    const int k0 = t << 5;
#pragma unroll
    for (int i = 0; i < 2; ++i) {
      int seg = (wave << 1) + i;                    // 0..7 -> rows seg*16..+15
      int row = (seg << 4) + lrow;
      const __hip_bfloat16* gpA = A + (size_t)(brow + row) * K + (k0 + (gc << 3));
      __builtin_amdgcn_global_load_lds(
          (const __attribute__((address_space(1))) void*)gpA,
          (__attribute__((address_space(3))) void*)(sA + (seg << 10)),
          16, 0, 0);
      const __hip_bfloat16* gpB = BT + (size_t)(bcol + row) * K + (k0 + (gc << 3));
      __builtin_amdgcn_global_load_lds(
          (const __attribute__((address_space(1))) void*)gpB,
          (__attribute__((address_space(3))) void*)(sB + (seg << 10)),
          16, 0, 0);
    }
  };

  STAGE(0); STAGE(1); STAGE(2);   // depth-3 prologue

  const int r15 = lane & 15;
  const int c   = lane >> 4;      // logical k-chunk 0..3 within BK=32

  for (int t = 0; t < nt; ++t) {
    if (t + 3 < nt) STAGE(t + 3);
    const int rem = nt - 1 - t;
    if (rem >= 3)      asm volatile("s_waitcnt vmcnt(12)" ::: "memory");
    else if (rem == 2) asm volatile("s_waitcnt vmcnt(8)"  ::: "memory");
    else if (rem == 1) asm volatile("s_waitcnt vmcnt(4)"  ::: "memory");
    else               asm volatile("s_waitcnt vmcnt(0)"  ::: "memory");
    __builtin_amdgcn_s_barrier();             // all waves: tile t staged everywhere
    __builtin_amdgcn_sched_barrier(0);        // no ds_read hoist above barrier

    char* sA = smem + (t % 5) * 16384;
    char* sB = sA + 8192;
    bf16x8 af[4], bfv[4];
#pragma unroll
    for (int f = 0; f < 4; ++f) {
      int ar = wm + (f << 4) + r15;
      af[f]  = *reinterpret_cast<const bf16x8*>(sA + ar * 64 + ((c ^ ((ar >> 1) & 3)) << 4));
      int br = wn + (f << 4) + r15;
      bfv[f] = *reinterpret_cast<const bf16x8*>(sB + br * 64 + ((c ^ ((br >> 1) & 3)) << 4));
    }
#pragma unroll
    for (int fm = 0; fm < 4; ++fm)
#pragma unroll
      for (int fn = 0; fn < 4; ++fn)
        acc[fm][fn] = __builtin_amdgcn_mfma_f32_16x16x32_bf16(af[fm], bfv[fn], acc[fm][fn], 0, 0, 0);
  }

  // epilogue: C/D layout col=lane&15, row=(lane>>4)*4+reg   [m89-verified]
  const int hi4 = (lane >> 4) << 2;
#pragma unroll
  for (int fn = 0; fn < 4; ++fn) {
    int col = bcol + wn + (fn << 4) + r15;
    float bv = bias[col];
#pragma unroll
    for (int fm = 0; fm < 4; ++fm) {
      int row0 = brow + wm + (fm << 4) + hi4;
#pragma unroll
      for (int r = 0; r < 4; ++r) {
        float v = acc[fm][fn][r] + bv;
        if (ADD_EXTRA) {
          int b = bids[row0 + r];
          v += extra[(size_t)b * P + col];
        }
        if (ACT) v = lrelu_f(v);
        size_t oidx = (size_t)(row0 + r) * P + col;
        if (BF16OUT) reinterpret_cast<__hip_bfloat16*>(out)[oidx] = __float2bfloat16(v);
        else         reinterpret_cast<float*>(out)[oidx] = v;
      }
    }
  }
}

extern "C" void kernel_launch(void* const* d_in, const int* in_sizes, int n_in,
                              void* d_out, int out_size, void* d_ws, size_t ws_size,
                              hipStream_t stream) {
  const float* x      = (const float*)d_in[0];
  const int*   bids   = (const int*)  d_in[1];
  const float* ge_W0  = (const float*)d_in[2];
  const float* ge_b0  = (const float*)d_in[3];
  const float* ge_Wh  = (const float*)d_in[4];
  const float* ge_bh  = (const float*)d_in[5];
  const float* ge_Wo  = (const float*)d_in[6];
  const float* ge_bo  = (const float*)d_in[7];
  const float* in_W   = (const float*)d_in[8];
  const float* in_b   = (const float*)d_in[9];
  const float* ag_W   = (const float*)d_in[10];
  const float* ag_b   = (const float*)d_in[11];
  const float* psi_Wh = (const float*)d_in[12];
  const float* psi_bh = (const float*)d_in[13];
  const float* psi_Wo = (const float*)d_in[14];
  const float* psi_bo = (const float*)d_in[15];

  char* ws = (char*)d_ws;
  __hip_bfloat16* geW0T   = (__hip_bfloat16*)(ws + 0);        // [512][128]
  __hip_bfloat16* geWh0T  = (__hip_bfloat16*)(ws + 131072);   // [512][512]
  __hip_bfloat16* geWh1T  = (__hip_bfloat16*)(ws + 655360);   // [512][512]
  __hip_bfloat16* geWoT   = (__hip_bfloat16*)(ws + 1179648);  // [256][512]
  __hip_bfloat16* inWT    = (__hip_bfloat16*)(ws + 1441792);  // [512][128]
  __hip_bfloat16* agWT    = (__hip_bfloat16*)(ws + 1572864);  // [512][256]
  __hip_bfloat16* psiWh0T = (__hip_bfloat16*)(ws + 1835008);  // [512][512]
  __hip_bfloat16* psiWh1T = (__hip_bfloat16*)(ws + 2359296);  // [512][512]
  __hip_bfloat16* psiWh2T = (__hip_bfloat16*)(ws + 2883584);  // [512][512]
  __hip_bfloat16* psiWoT  = (__hip_bfloat16*)(ws + 3407872);  // [128][512]
  __hip_bfloat16* sigma   = (__hip_bfloat16*)(ws + 3538944);  // [1024][256] bf16
  float*          sh      = (float*)         (ws + 4063232);  // [1024][512] f32
  float*          sums    = (float*)         (ws + 6160384);  // [1024][256] f32
  const size_t base = 7340032;  // 7 MiB

  size_t CH = 0;
  {
    const size_t cands[11] = {131072, 65536, 32768, 16384, 8192, 4096, 2048, 1024, 512, 256, 128};
    for (int i = 0; i < 11; ++i)
      if (ws_size >= base + cands[i] * 2304ull) { CH = cands[i]; break; }
  }
  if (CH == 0) {
    sentinel<<<1, 64, 0, stream>>>((float*)d_out, 100000000.f + (float)(ws_size / 1024));
    return;
  }

  __hip_bfloat16* xc  = (__hip_bfloat16*)(ws + base);
  __hip_bfloat16* pp0 = (__hip_bfloat16*)(ws + base + CH * 256);
  __hip_bfloat16* pp1 = (__hip_bfloat16*)(ws + base + CH * 256 + CH * 1024);

  dim3 blk(256);
  const int nch = (int)(N_NODES / CH);
  const unsigned mb = (unsigned)(CH >> 7);
  dim3 g4(4, mb), g2(2, mb), g1(1, mb);   // bcol fast, brow slow

  // ---- weight conversions (LDS-tiled transpose, grid = (P/32, K/32)) ----
  wt_conv<<<dim3(16, 4),  blk, 0, stream>>>(ge_W0,           geW0T,   128, 512);
  wt_conv<<<dim3(16, 16), blk, 0, stream>>>(ge_Wh,           geWh0T,  512, 512);
  wt_conv<<<dim3(16, 16), blk, 0, stream>>>(ge_Wh + 262144,  geWh1T,  512, 512);
  wt_conv<<<dim3(8, 16),  blk, 0, stream>>>(ge_Wo,           geWoT,   512, 256);
  wt_conv<<<dim3(16, 4),  blk, 0, stream>>>(in_W,            inWT,    128, 512);
  wt_conv<<<dim3(16, 8),  blk, 0, stream>>>(ag_W,            agWT,    256, 512);
  wt_conv<<<dim3(16, 16), blk, 0, stream>>>(psi_Wh,          psiWh0T, 512, 512);
  wt_conv<<<dim3(16, 16), blk, 0, stream>>>(psi_Wh + 262144, psiWh1T, 512, 512);
  wt_conv<<<dim3(16, 16), blk, 0, stream>>>(psi_Wh + 524288, psiWh2T, 512, 512);
  wt_conv<<<dim3(4, 16),  blk, 0, stream>>>(psi_Wo,          psiWoT,  512, 128);

  for (int c = 0; c < nch; ++c) {
    const size_t rb = (size_t)c * CH;
    xconv<<<(unsigned)(CH >> 3), blk, 0, stream>>>(x + rb * 128, xc, (int)(CH * 32));
    gemm_mfma<1,1,0><<<g4, blk, 0, stream>>>(xc,  geW0T,  ge_b0,     nullptr, nullptr, pp0, 128, 512);
    gemm_mfma<1,1,0><<<g4, blk, 0, stream>>>(pp0, geWh0T, ge_bh,     nullptr, nullptr, pp1, 512, 512);
    gemm_mfma<1,1,0><<<g4, blk, 0, stream>>>(pp1, geWh1T, ge_bh+512, nullptr, nullptr, pp0, 512, 512);
    gemm_mfma<1,1,0><<<g2, blk, 0, stream>>>(pp0, geWoT,  ge_bo,     nullptr, nullptr, pp1, 512, 256);
    if (c == 0) seg_accum<1><<<NUM_G, blk, 0, stream>>>(pp1, bids, sums, (int)rb, (int)CH);
    else        seg_accum<0><<<NUM_G, blk, 0, stream>>>(pp1, bids, sums, (int)rb, (int)CH);
  }

  sigma_fin<<<NUM_G, blk, 0, stream>>>(sums, bids, sigma);
  gemm_mfma<0,0,0><<<dim3(4, 8), blk, 0, stream>>>(sigma, agWT, ag_b, nullptr, nullptr, sh, 256, 512);

  for (int c = 0; c < nch; ++c) {
    const size_t rb = (size_t)c * CH;
    xconv<<<(unsigned)(CH >> 3), blk, 0, stream>>>(x + rb * 128, xc, (int)(CH * 32));
    gemm_mfma<1,1,1><<<g4, blk, 0, stream>>>(xc,  inWT,    in_b,        sh,      bids + rb, pp0, 128, 512);
    gemm_mfma<1,1,0><<<g4, blk, 0, stream>>>(pp0, psiWh0T, psi_bh,      nullptr, nullptr,   pp1, 512, 512);
    gemm_mfma<1,1,0><<<g4, blk, 0, stream>>>(pp1, psiWh1T, psi_bh+512,  nullptr, nullptr,   pp0, 512, 512);
    gemm_mfma<1,1,0><<<g4, blk, 0, stream>>>(pp0, psiWh2T, psi_bh+1024, nullptr, nullptr,   pp1, 512, 512);
    gemm_mfma<0,0,0><<<g1, blk, 0, stream>>>(pp1, psiWoT,  psi_bo,      nullptr, nullptr,
                                             (float*)d_out + rb * 128, 512, 128);
  }
}

// Round 9
// 678.805 us; speedup vs baseline: 1.5158x; 1.4646x over previous
//
#include <hip/hip_runtime.h>
#include <hip/hip_bf16.h>

// Sumformer inner block -- R9: FUSED layer-chain kernels.
// R8 post-mortem: per-GEMM dur == HBM-traffic/BW (200MB @3.2TB/s = 63us) ->
// memory-bound on inter-layer activations. Fix: one block owns 64 nodes and
// runs the whole MLP chain with activations LDS-resident; weights streamed
// from L2 via counted-vmcnt gload_lds double-buffer (R8-verified machinery).
// Operand swap: mfma(A=weights, B=act) -> C/D col=node,row=neuron so epilogue
// packs 4 consecutive neurons into one 8B ds_write (act stays [node][k]).
// ge-final fuses segment-sum (atomicAdd per graph-run); ne never materialized.
// psi-L1 fuses the sh[bid] gather; psi-final writes d_out directly.

typedef __attribute__((ext_vector_type(8))) short bf16x8;
typedef __attribute__((ext_vector_type(4))) float f32x4;

#define N_NODES 131072
#define NUM_G   1024

__device__ __forceinline__ float lrelu_f(float v) { return v >= 0.f ? v : 0.01f * v; }
__device__ __forceinline__ short f2bs(float f) {
  union { __hip_bfloat16 h; short s; } q; q.h = __float2bfloat16(f); return q.s;
}
__device__ __forceinline__ float bs2f(unsigned short u) {
  unsigned x = ((unsigned)u) << 16; return __uint_as_float(x);
}

__global__ void sentinel(float* out, float v) {
  if (blockIdx.x == 0 && threadIdx.x == 0) out[0] = v;
}

// WT[p][k] = bf16(W[k][p]);  W is [K][P].  LDS-tiled 32x32 transpose. (R8, green)
__global__ void wt_conv(const float* __restrict__ W, __hip_bfloat16* __restrict__ WT, int K, int P) {
  __shared__ float tile[32][33];
  const int p0 = blockIdx.x << 5, k0 = blockIdx.y << 5;
  const int tx = threadIdx.x & 31, ty = threadIdx.x >> 5;
#pragma unroll
  for (int i = 0; i < 4; ++i) {
    int r = ty + (i << 3);
    tile[r][tx] = W[(size_t)(k0 + r) * P + p0 + tx];
  }
  __syncthreads();
#pragma unroll
  for (int i = 0; i < 4; ++i) {
    int r = ty + (i << 3);
    WT[(size_t)(p0 + r) * K + k0 + tx] = __float2bfloat16(tile[tx][r]);
  }
}

__global__ void sigma_fin(const float* __restrict__ sums,
                          const int* __restrict__ ids,
                          __hip_bfloat16* __restrict__ sigma) {
  int g = blockIdx.x;
  int k = threadIdx.x;
  int lo = 0, hi = N_NODES;
  while (lo < hi) { int m = (lo + hi) >> 1; if (ids[m] < g) lo = m + 1; else hi = m; }
  int s = lo;
  hi = N_NODES;
  while (lo < hi) { int m = (lo + hi) >> 1; if (ids[m] < g + 1) lo = m + 1; else hi = m; }
  int e = lo;
  float c = (float)(e - s);
  sigma[g * 256 + k] = __float2bfloat16(sums[g * 256 + k] / fmaxf(c, 1.f));
}

// R8 gemm (green): used only for sh = sigma @ agWT + agb  [1024x256 x 256x512]
template<int ACT, int BF16OUT>
__global__ __launch_bounds__(256)
void gemm_mfma(const __hip_bfloat16* __restrict__ A,
               const __hip_bfloat16* __restrict__ BT,
               const float* __restrict__ bias,
               void* __restrict__ out, int K, int P) {
  __shared__ __attribute__((aligned(128))) char smem[81920];
  const int tid  = threadIdx.x;
  const int lane = tid & 63;
  const int wave = tid >> 6;
  const int bcol = blockIdx.x << 7;
  const int brow = blockIdx.y << 7;
  const int wm = (wave >> 1) << 6;
  const int wn = (wave & 1) << 6;
  const int lrow = lane >> 2;
  const int gc   = (lane & 3) ^ ((lane >> 3) & 3);
  f32x4 acc[4][4] = {};
  const int nt = K >> 5;
  auto STAGE = [&](int t) {
    char* sA = smem + (t % 5) * 16384;
    char* sB = sA + 8192;
    const int k0 = t << 5;
#pragma unroll
    for (int i = 0; i < 2; ++i) {
      int seg = (wave << 1) + i;
      int row = (seg << 4) + lrow;
      __builtin_amdgcn_global_load_lds(
          (const __attribute__((address_space(1))) void*)(A + (size_t)(brow + row) * K + (k0 + (gc << 3))),
          (__attribute__((address_space(3))) void*)(sA + (seg << 10)), 16, 0, 0);
      __builtin_amdgcn_global_load_lds(
          (const __attribute__((address_space(1))) void*)(BT + (size_t)(bcol + row) * K + (k0 + (gc << 3))),
          (__attribute__((address_space(3))) void*)(sB + (seg << 10)), 16, 0, 0);
    }
  };
  STAGE(0); STAGE(1); STAGE(2);
  const int r15 = lane & 15;
  const int c   = lane >> 4;
  for (int t = 0; t < nt; ++t) {
    if (t + 3 < nt) STAGE(t + 3);
    const int rem = nt - 1 - t;
    if (rem >= 3)      asm volatile("s_waitcnt vmcnt(12)" ::: "memory");
    else if (rem == 2) asm volatile("s_waitcnt vmcnt(8)"  ::: "memory");
    else if (rem == 1) asm volatile("s_waitcnt vmcnt(4)"  ::: "memory");
    else               asm volatile("s_waitcnt vmcnt(0)"  ::: "memory");
    __builtin_amdgcn_s_barrier();
    __builtin_amdgcn_sched_barrier(0);
    char* sA = smem + (t % 5) * 16384;
    char* sB = sA + 8192;
    bf16x8 af[4], bfv[4];
#pragma unroll
    for (int f = 0; f < 4; ++f) {
      int ar = wm + (f << 4) + r15;
      af[f]  = *reinterpret_cast<const bf16x8*>(sA + ar * 64 + ((c ^ ((ar >> 1) & 3)) << 4));
      int br = wn + (f << 4) + r15;
      bfv[f] = *reinterpret_cast<const bf16x8*>(sB + br * 64 + ((c ^ ((br >> 1) & 3)) << 4));
    }
#pragma unroll
    for (int fm = 0; fm < 4; ++fm)
#pragma unroll
      for (int fn = 0; fn < 4; ++fn)
        acc[fm][fn] = __builtin_amdgcn_mfma_f32_16x16x32_bf16(af[fm], bfv[fn], acc[fm][fn], 0, 0, 0);
  }
  const int hi4 = (lane >> 4) << 2;
#pragma unroll
  for (int fn = 0; fn < 4; ++fn) {
    int col = bcol + wn + (fn << 4) + r15;
    float bv = bias[col];
#pragma unroll
    for (int fm = 0; fm < 4; ++fm) {
      int row0 = brow + wm + (fm << 4) + hi4;
#pragma unroll
      for (int r = 0; r < 4; ++r) {
        float v = acc[fm][fn][r] + bv;
        if (ACT) v = lrelu_f(v);
        size_t oidx = (size_t)(row0 + r) * P + col;
        if (BF16OUT) reinterpret_cast<__hip_bfloat16*>(out)[oidx] = __float2bfloat16(v);
        else         reinterpret_cast<float*>(out)[oidx] = v;
      }
    }
  }
}

// ---------------- fused layer-chain ----------------
// act LDS: [64 nodes][512 k] bf16, row stride 1024B (64 16B-chunks), chunk
// swizzle c ^= (node&7).  weight LDS: dbuf [P rows][32 k], row stride 64B,
// chunk swizzle c ^= ((p>>1)&3) (R8-verified).  8 waves: wave w owns neuron
// range p0w = w*(P/8), all 64 nodes (4 n-frags).
// MODE: 0 = bias+lrelu -> act;  1 = + sh[bid[node]] gather (psi L1);
//       2 = ge-final: bias+lrelu -> act, then fused segment-sum -> atomicAdd;
//       3 = psi-final: bias -> d_out (no act).

__device__ __forceinline__ void gll16(const __hip_bfloat16* g, char* l) {
  __builtin_amdgcn_global_load_lds((const __attribute__((address_space(1))) void*)g,
                                   (__attribute__((address_space(3))) void*)l, 16, 0, 0);
}

template<int K, int P, int MODE>
__device__ __forceinline__ void layer_run(
    char* actmem, char* wbuf, const __hip_bfloat16* __restrict__ WT,
    const float* __restrict__ bias, const float* __restrict__ sh,
    const int* bids_lds, float* __restrict__ gout, int nbase, int tid) {
  const int w = tid >> 6, lane = tid & 63;
  const int r15 = lane & 15, khi = lane >> 4;
  constexpr int MF = P / 128;          // m-frags per wave
  constexpr int SI = P / 128;          // stage gload_lds per thread per tile
  constexpr int NT = K / 32;
  const int p0w = w * (P >> 3);
  const int wb64x16 = (w << 6) << 4;   // wave-uniform LDS dest offset

  f32x4 acc[MF][4];
#pragma unroll
  for (int a = 0; a < MF; ++a)
#pragma unroll
    for (int b = 0; b < 4; ++b) acc[a][b] = f32x4{0.f, 0.f, 0.f, 0.f};

  auto stagew = [&](int t) {
    char* wb = wbuf + ((t & 1) << 15);
    const int k0 = t << 5;
#pragma unroll
    for (int i = 0; i < SI; ++i) {
      int L = (i << 9) + tid;
      int row = L >> 2, pc = L & 3;
      int gc = pc ^ ((row >> 1) & 3);
      gll16(WT + (size_t)row * K + k0 + (gc << 3), wb + (i << 13) + wb64x16);
    }
  };

  stagew(0);
  for (int t = 0; t < NT; ++t) {
    if (t + 1 < NT) {
      stagew(t + 1);
      if constexpr (SI == 4)      asm volatile("s_waitcnt vmcnt(4)" ::: "memory");
      else if constexpr (SI == 2) asm volatile("s_waitcnt vmcnt(2)" ::: "memory");
      else                        asm volatile("s_waitcnt vmcnt(1)" ::: "memory");
    } else {
      asm volatile("s_waitcnt vmcnt(0)" ::: "memory");
    }
    __builtin_amdgcn_s_barrier();          // tile t staged by all waves
    __builtin_amdgcn_sched_barrier(0);

    char* wb = wbuf + ((t & 1) << 15);
    bf16x8 bf[4], af[MF];
#pragma unroll
    for (int ni = 0; ni < 4; ++ni) {
      int nd = (ni << 4) + r15;
      int ch = ((t << 2) + khi) ^ (nd & 7);
      bf[ni] = *reinterpret_cast<const bf16x8*>(actmem + (nd << 10) + (ch << 4));
    }
#pragma unroll
    for (int mi = 0; mi < MF; ++mi) {
      int p = p0w + (mi << 4) + r15;
      int ch = khi ^ ((p >> 1) & 3);
      af[mi] = *reinterpret_cast<const bf16x8*>(wb + (p << 6) + (ch << 4));
    }
#pragma unroll
    for (int mi = 0; mi < MF; ++mi)
#pragma unroll
      for (int ni = 0; ni < 4; ++ni)
        acc[mi][ni] = __builtin_amdgcn_mfma_f32_16x16x32_bf16(af[mi], bf[ni], acc[mi][ni], 0, 0, 0);
    __builtin_amdgcn_s_barrier();          // all reads of wb[t&1] done (safe for t+2 stage)
  }

  // ---- epilogue ----
  if constexpr (MODE == 3) {
    // psi-final: P=128, MF=1, bias only, write d_out f32
    const int pb = p0w + (khi << 2);
    f32x4 bv = *reinterpret_cast<const f32x4*>(bias + pb);
#pragma unroll
    for (int ni = 0; ni < 4; ++ni) {
      int nd = (ni << 4) + r15;
      f32x4 v = acc[0][ni] + bv;
      *reinterpret_cast<f32x4*>(gout + ((size_t)(nbase + nd) << 7) + pb) = v;
    }
  } else {
#pragma unroll
    for (int mi = 0; mi < MF; ++mi) {
      const int pb = p0w + (mi << 4) + (khi << 2);
      f32x4 bv = *reinterpret_cast<const f32x4*>(bias + pb);
#pragma unroll
      for (int ni = 0; ni < 4; ++ni) {
        int nd = (ni << 4) + r15;
        f32x4 v = acc[mi][ni] + bv;
        if constexpr (MODE == 1) {
          int g = bids_lds[nd];
          f32x4 s = *reinterpret_cast<const f32x4*>(sh + ((size_t)g << 9) + pb);
          v = v + s;
        }
        short4 u;
        u.x = f2bs(lrelu_f(v[0])); u.y = f2bs(lrelu_f(v[1]));
        u.z = f2bs(lrelu_f(v[2])); u.w = f2bs(lrelu_f(v[3]));
        int ch = (pb >> 3) ^ (nd & 7);
        *reinterpret_cast<short4*>(actmem + (nd << 10) + (ch << 4) + ((pb & 4) << 1)) = u;
      }
    }
    __syncthreads();   // act fully written before next layer reads (or seg-sum)

    if constexpr (MODE == 2) {
      // fused segment-sum of ne (=act[64][256]) into gout=sums via atomicAdd
      const int c = tid & 255, h = tid >> 8;
      float a = 0.f;
      int gp = bids_lds[h << 5];
      for (int r = 0; r < 32; ++r) {
        int nd = (h << 5) + r;
        int ch = (c >> 3) ^ (nd & 7);
        unsigned short uv = *reinterpret_cast<const unsigned short*>(
            actmem + (nd << 10) + (ch << 4) + ((c & 7) << 1));
        float v = bs2f(uv);
        int g = bids_lds[nd];
        if (g != gp) { atomicAdd(gout + ((size_t)gp << 8) + c, a); a = 0.f; gp = g; }
        a += v;
      }
      atomicAdd(gout + ((size_t)gp << 8) + c, a);
    }
  }
}

template<int PSI>
__global__ __launch_bounds__(512, 1)
void fused_chain(const float* __restrict__ x, const int* __restrict__ bids,
                 const __hip_bfloat16* __restrict__ Wa, const float* __restrict__ ba,
                 const __hip_bfloat16* __restrict__ Wb, const float* __restrict__ bb,
                 const __hip_bfloat16* __restrict__ Wc, const float* __restrict__ bc,
                 const __hip_bfloat16* __restrict__ Wd, const float* __restrict__ bd,
                 const __hip_bfloat16* __restrict__ We, const float* __restrict__ be,
                 const float* __restrict__ sh, float* __restrict__ gout) {
  __shared__ __attribute__((aligned(128))) char actmem[65536];
  __shared__ __attribute__((aligned(128))) char wbuf[65536];
  __shared__ int bids_lds[64];
  const int tid = threadIdx.x;
  const int nbase = blockIdx.x << 6;
  if (tid < 64) bids_lds[tid] = bids[nbase + tid];

  // stage x[64][128] f32 -> act bf16 swizzled
#pragma unroll
  for (int i = 0; i < 2; ++i) {
    int L = (i << 9) + tid;
    int n = L >> 4, c = L & 15;
    const float* xp = x + (((size_t)(nbase + n)) << 7) + (c << 3);
    float4 v0 = *reinterpret_cast<const float4*>(xp);
    float4 v1 = *reinterpret_cast<const float4*>(xp + 4);
    bf16x8 pk;
    pk[0] = f2bs(v0.x); pk[1] = f2bs(v0.y); pk[2] = f2bs(v0.z); pk[3] = f2bs(v0.w);
    pk[4] = f2bs(v1.x); pk[5] = f2bs(v1.y); pk[6] = f2bs(v1.z); pk[7] = f2bs(v1.w);
    *reinterpret_cast<bf16x8*>(actmem + (n << 10) + ((c ^ (n & 7)) << 4)) = pk;
  }
  __syncthreads();

  if constexpr (PSI == 0) {
    layer_run<128, 512, 0>(actmem, wbuf, Wa, ba, nullptr, bids_lds, nullptr, nbase, tid);
    layer_run<512, 512, 0>(actmem, wbuf, Wb, bb, nullptr, bids_lds, nullptr, nbase, tid);
    layer_run<512, 512, 0>(actmem, wbuf, Wc, bc, nullptr, bids_lds, nullptr, nbase, tid);
    layer_run<512, 256, 2>(actmem, wbuf, Wd, bd, nullptr, bids_lds, gout, nbase, tid);
  } else {
    layer_run<128, 512, 1>(actmem, wbuf, Wa, ba, sh, bids_lds, nullptr, nbase, tid);
    layer_run<512, 512, 0>(actmem, wbuf, Wb, bb, nullptr, bids_lds, nullptr, nbase, tid);
    layer_run<512, 512, 0>(actmem, wbuf, Wc, bc, nullptr, bids_lds, nullptr, nbase, tid);
    layer_run<512, 512, 0>(actmem, wbuf, Wd, bd, nullptr, bids_lds, nullptr, nbase, tid);
    layer_run<512, 128, 3>(actmem, wbuf, We, be, nullptr, bids_lds, gout, nbase, tid);
  }
}

extern "C" void kernel_launch(void* const* d_in, const int* in_sizes, int n_in,
                              void* d_out, int out_size, void* d_ws, size_t ws_size,
                              hipStream_t stream) {
  const float* x      = (const float*)d_in[0];
  const int*   bids   = (const int*)  d_in[1];
  const float* ge_W0  = (const float*)d_in[2];
  const float* ge_b0  = (const float*)d_in[3];
  const float* ge_Wh  = (const float*)d_in[4];
  const float* ge_bh  = (const float*)d_in[5];
  const float* ge_Wo  = (const float*)d_in[6];
  const float* ge_bo  = (const float*)d_in[7];
  const float* in_W   = (const float*)d_in[8];
  const float* in_b   = (const float*)d_in[9];
  const float* ag_W   = (const float*)d_in[10];
  const float* ag_b   = (const float*)d_in[11];
  const float* psi_Wh = (const float*)d_in[12];
  const float* psi_bh = (const float*)d_in[13];
  const float* psi_Wo = (const float*)d_in[14];
  const float* psi_bo = (const float*)d_in[15];

  char* ws = (char*)d_ws;
  __hip_bfloat16* geW0T   = (__hip_bfloat16*)(ws + 0);        // [512][128]
  __hip_bfloat16* geWh0T  = (__hip_bfloat16*)(ws + 131072);   // [512][512]
  __hip_bfloat16* geWh1T  = (__hip_bfloat16*)(ws + 655360);   // [512][512]
  __hip_bfloat16* geWoT   = (__hip_bfloat16*)(ws + 1179648);  // [256][512]
  __hip_bfloat16* inWT    = (__hip_bfloat16*)(ws + 1441792);  // [512][128]
  __hip_bfloat16* agWT    = (__hip_bfloat16*)(ws + 1572864);  // [512][256]
  __hip_bfloat16* psiWh0T = (__hip_bfloat16*)(ws + 1835008);  // [512][512]
  __hip_bfloat16* psiWh1T = (__hip_bfloat16*)(ws + 2359296);  // [512][512]
  __hip_bfloat16* psiWh2T = (__hip_bfloat16*)(ws + 2883584);  // [512][512]
  __hip_bfloat16* psiWoT  = (__hip_bfloat16*)(ws + 3407872);  // [128][512]
  __hip_bfloat16* sigma   = (__hip_bfloat16*)(ws + 3538944);  // [1024][256] bf16
  float*          sh      = (float*)         (ws + 4063232);  // [1024][512] f32
  float*          sums    = (float*)         (ws + 6160384);  // [1024][256] f32

  if (ws_size < 7340032) {
    sentinel<<<1, 64, 0, stream>>>((float*)d_out, 100000000.f + (float)(ws_size / 1024));
    return;
  }

  dim3 blk(256);
  hipMemsetAsync(sums, 0, NUM_G * 256 * sizeof(float), stream);

  // ---- weight conversions (grid = (P/32, K/32)) ----
  wt_conv<<<dim3(16, 4),  blk, 0, stream>>>(ge_W0,           geW0T,   128, 512);
  wt_conv<<<dim3(16, 16), blk, 0, stream>>>(ge_Wh,           geWh0T,  512, 512);
  wt_conv<<<dim3(16, 16), blk, 0, stream>>>(ge_Wh + 262144,  geWh1T,  512, 512);
  wt_conv<<<dim3(8, 16),  blk, 0, stream>>>(ge_Wo,           geWoT,   512, 256);
  wt_conv<<<dim3(16, 4),  blk, 0, stream>>>(in_W,            inWT,    128, 512);
  wt_conv<<<dim3(16, 8),  blk, 0, stream>>>(ag_W,            agWT,    256, 512);
  wt_conv<<<dim3(16, 16), blk, 0, stream>>>(psi_Wh,          psiWh0T, 512, 512);
  wt_conv<<<dim3(16, 16), blk, 0, stream>>>(psi_Wh + 262144, psiWh1T, 512, 512);
  wt_conv<<<dim3(16, 16), blk, 0, stream>>>(psi_Wh + 524288, psiWh2T, 512, 512);
  wt_conv<<<dim3(4, 16),  blk, 0, stream>>>(psi_Wo,          psiWoT,  512, 128);

  // ---- ge chain fused (writes segment sums) ----
  fused_chain<0><<<N_NODES / 64, 512, 0, stream>>>(
      x, bids, geW0T, ge_b0, geWh0T, ge_bh, geWh1T, ge_bh + 512, geWoT, ge_bo,
      nullptr, nullptr, nullptr, sums);

  // ---- sigma; sh = sigma @ agWT + agb ----
  sigma_fin<<<NUM_G, blk, 0, stream>>>(sums, bids, sigma);
  gemm_mfma<0, 0><<<dim3(4, 8), blk, 0, stream>>>(sigma, agWT, ag_b, sh, 256, 512);

  // ---- psi chain fused (writes d_out) ----
  fused_chain<1><<<N_NODES / 64, 512, 0, stream>>>(
      x, bids, inWT, in_b, psiWh0T, psi_bh, psiWh1T, psi_bh + 512,
      psiWh2T, psi_bh + 1024, psiWoT, psi_bo, sh, (float*)d_out);
}